// Round 3
// baseline (209.848 us; speedup 1.0000x reference)
//
#include <hip/hip_runtime.h>

namespace {

typedef unsigned int uint;
typedef unsigned short ushort_t;
typedef __attribute__((ext_vector_type(8))) short bf16x8;
typedef __attribute__((ext_vector_type(4))) float f32x4;

constexpr int N = 4, T = 2048, L = 2048;
constexpr int DQIN = 32, DQK = 64;

// workspace layout (float-sized slots); ~12.8 MB
constexpr int VI_SZ = 3 * N * 64 * L;  // ushort pairs [dim row][8l-group][hi8|lo8], as float slots
constexpr int X_SZ = 3 * N * L;
constexpr int A_SZ = 3 * N * T;

union PK8 { int i[4]; bf16x8 s; };

// =================== fused prep kernel ===================
// [0,96): Q->a,g (one thread per (m,n,t)); [96,192): binary searches; [192,576): V transform
__global__ __launch_bounds__(256) void mm_prep(
    const float* __restrict__ ref_data, const float* __restrict__ ref_t,
    const float* __restrict__ d1, const float* __restrict__ t1,
    const float* __restrict__ d2, const float* __restrict__ t2,
    const float* __restrict__ d3, const float* __restrict__ t3,
    const float* __restrict__ Wq,
    const float* __restrict__ Wk1, const float* __restrict__ bk1,
    const float* __restrict__ Wv1, const float* __restrict__ bv1, const float* __restrict__ lt1,
    const float* __restrict__ Wk2, const float* __restrict__ bk2,
    const float* __restrict__ Wv2, const float* __restrict__ bv2, const float* __restrict__ lt2,
    const float* __restrict__ Wk3, const float* __restrict__ bk3,
    const float* __restrict__ Wv3, const float* __restrict__ bv3, const float* __restrict__ lt3,
    float* __restrict__ Aq, float* __restrict__ Gq, int* __restrict__ Cq,
    ushort_t* __restrict__ VI, float* __restrict__ X) {
  const int b = blockIdx.x;
  const int tid = threadIdx.x;

  if (b < 96) {
    // ---- Q path, one thread per (m, n*T+t); block-uniform modality m = b/32 ----
    const int m = b >> 5;
    const int idx = (b & 31) * 256 + tid;  // n*T + t
    __shared__ float sWq[DQIN * DQK];
    __shared__ float sWk[DQK];
    __shared__ float sbk[DQK];
    const float* Wk = (m == 0) ? Wk1 : (m == 1 ? Wk2 : Wk3);
    const float* bk = (m == 0) ? bk1 : (m == 1 ? bk2 : bk3);
    const float* lt = (m == 0) ? lt1 : (m == 1 ? lt2 : lt3);
    for (int i = tid; i < DQIN * DQK; i += 256) sWq[i] = Wq[i];
    if (tid < DQK) { sWk[tid] = Wk[tid]; sbk[tid] = bk[tid]; }
    __syncthreads();
    float x[DQIN];
    const float* rp = ref_data + idx * DQIN;
#pragma unroll
    for (int i = 0; i < DQIN; i++) x[i] = rp[i];
    float qr[DQK];
#pragma unroll
    for (int j = 0; j < DQK; j += 4) {
      float4 acc4 = make_float4(0.f, 0.f, 0.f, 0.f);
#pragma unroll
      for (int i = 0; i < DQIN; i++) {
        const float4 w = *(const float4*)&sWq[i * DQK + j];
        acc4.x = fmaf(x[i], w.x, acc4.x);
        acc4.y = fmaf(x[i], w.y, acc4.y);
        acc4.z = fmaf(x[i], w.z, acc4.z);
        acc4.w = fmaf(x[i], w.w, acc4.w);
      }
      qr[j] = acc4.x; qr[j + 1] = acc4.y; qr[j + 2] = acc4.z; qr[j + 3] = acc4.w;
    }
    const float rs = __expf(-0.5f * lt[0]);
    float g = 0.f, h = 0.f;
#pragma unroll
    for (int j = 1; j < DQK; j++) {
      g = fmaf(qr[j], sWk[j - 1], g);
      h = fmaf(qr[j], sbk[j - 1], h);
    }
    g += sWk[DQK - 1];
    h += sbk[DQK - 1];
    Aq[m * (N * T) + idx] = (qr[0] - h) * rs;
    Gq[m * (N * T) + idx] = g * rs;
  } else if (b < 192) {
    const int sidx = (b - 96) * 256 + tid;
    const int m = sidx >> 13;
    const int nt = sidx & 8191;
    const int n = nt >> 11;
    const float rt = ref_t[nt];
    const float* tml = ((m == 0) ? t1 : (m == 1 ? t2 : t3)) + n * L;
    int lo = 0, hi = L;
    while (lo < hi) {
      const int mid = (lo + hi) >> 1;
      if (tml[mid] <= rt) lo = mid + 1; else hi = mid;
    }
    Cq[m * 8192 + nt] = lo;
  } else {
    const int vb = b - 192;          // 0..383
    const int mn = vb >> 5;          // m*N+n
    const int m = mn >> 2, n = mn & 3;
    const int lseg0 = (vb & 31) * 64;
    const float* dm = (m == 0) ? d1 : (m == 1 ? d2 : d3);
    const float* Wv = (m == 0) ? Wv1 : (m == 1 ? Wv2 : Wv3);
    const float* bv = (m == 0) ? bv1 : (m == 1 ? bv2 : bv3);
    const int cdim = tid & 63;
    const int qq = tid >> 6;
    const int l0 = lseg0 + qq * 16;

    float Wc[32];
#pragma unroll
    for (int i = 0; i < 32; i++) Wc[i] = Wv[i * 64 + cdim];
    const float bvc = bv[cdim];

    uint hi16[16], lo16[16];
#pragma unroll 4
    for (int k = 0; k < 16; k++) {
      const float* dp = dm + (size_t)(n * L + l0 + k) * 34;
      float acc = bvc;
#pragma unroll
      for (int i = 0; i < 32; i++) acc = fmaf(dp[i], Wc[i], acc);
      uint u = __float_as_uint(acc);
      uint h = (u + 0x7fffu + ((u >> 16) & 1u)) & 0xffff0000u;
      float res = acc - __uint_as_float(h);
      uint ul = __float_as_uint(res);
      uint hl = (ul + 0x7fffu + ((ul >> 16) & 1u)) >> 16;
      hi16[k] = h >> 16;
      lo16[k] = hl;
    }
    int pkh[8], pkl[8];
#pragma unroll
    for (int p = 0; p < 8; p++) {
      pkh[p] = (int)(hi16[2 * p] | (hi16[2 * p + 1] << 16));
      pkl[p] = (int)(lo16[2 * p] | (lo16[2 * p + 1] << 16));
    }
    ushort_t* dst = VI + (size_t)(mn * 64 + cdim) * (2 * L) + (l0 >> 3) * 16;
    *(int4*)dst = make_int4(pkh[0], pkh[1], pkh[2], pkh[3]);
    *(int4*)(dst + 8) = make_int4(pkl[0], pkl[1], pkl[2], pkl[3]);
    *(int4*)(dst + 16) = make_int4(pkh[4], pkh[5], pkh[6], pkh[7]);
    *(int4*)(dst + 24) = make_int4(pkl[4], pkl[5], pkl[6], pkl[7]);

    if (tid < 64) {
      const int l = lseg0 + tid;
      X[mn * L + l] = dm[(size_t)(n * L + l) * 34 + 33];
    }
  }
}

// =================== main attention kernel ===================
// NO LDS, NO BARRIERS. Each wave owns one rowgroup (16 t-rows) and streams
// its 64-l chunks fully independently. V fragments (bf16 hi/lo pairs) and X
// are read straight from global: VI per mn is ~1MB and X 8KB — they live in
// L2/L3 (64 blocks share each mn), so LDS staging was pure overhead and its
// 2-barriers-per-chunk lockstep made the kernel latency-bound at 1.5
// waves/SIMD (r1/r2: MfmaUtil 7.5%, VALUBusy 21%, ~2400cy/chunk vs ~650cy
// of work). With no barriers the compiler freely hoists loads across chunk
// iterations and overlaps MFMA/VALU/trans per wave. Per-accumulator MFMA
// order unchanged -> output bitwise identical to r1/r2.
__global__ __launch_bounds__(128) void mm_attn_main(
    const ushort_t* __restrict__ VI, const float* __restrict__ X,
    const float* __restrict__ Aq, const float* __restrict__ Gq, const int* __restrict__ Cq,
    float* __restrict__ out) {
  const int b = blockIdx.x;
  const int mn = b % 12;
  const int j = b / 12;    // 0..63
  const int pj = 63 - j;   // heavy pairs (large c) first in dispatch order

  const int tid = threadIdx.x;
  const int lane = tid & 63;
  const int w = tid >> 6;              // wave 0/1
  const int q = lane >> 4;
  const int m16 = lane & 15;

  const int rg = pj * 2 + w;           // similar-c pair {2pj, 2pj+1}
  const int tbase = mn * T + rg * 16;

  const int c = Cq[tbase + m16];
  const int cmax = __shfl(c, 15, 64);  // c monotone in t
  const int cmin = __shfl(c, 0, 64);
  const int nch = (cmax + 63) >> 6;    // this wave's 64-l chunk count

  const float a = Aq[tbase + m16];
  const float g = Gq[tbase + m16];

  f32x4 acc[4];  // [hh*2+ct]: cols hh*32 + ct*16 + m16
#pragma unroll
  for (int i = 0; i < 4; i++) acc[i] = (f32x4){0.f, 0.f, 0.f, 0.f};
  float z = 0.f;

  const float* xg = X + mn * L;

  // per-lane V fragment base pointers, one per acc quadrant (hoisted):
  // dim row d = hh*32 + ct*16 + m16, row pitch 4096 ushorts (8KB);
  // l-group (k0/8) at +group*16 ushorts: hi8 at +0, lo8 at +8.
  const ushort_t* Vq[4];
#pragma unroll
  for (int hh = 0; hh < 2; hh++)
#pragma unroll
    for (int ct = 0; ct < 2; ct++)
      Vq[hh * 2 + ct] =
          VI + (size_t)(mn * 64 + hh * 32 + ct * 16 + m16) * 4096 + q * 16;

  for (int ch = 0; ch < nch; ch++) {
    const int base = ch << 6;
    const bool inter = (base + 64 <= cmin);  // all 16 rows fully active
#pragma unroll
    for (int kk = 0; kk < 2; kk++) {
      const int k0 = base + kk * 32 + q * 8;
      const float4 xa = *(const float4*)&xg[k0];
      const float4 xb = *(const float4*)&xg[k0 + 4];
      const float xs[8] = {xa.x, xa.y, xa.z, xa.w, xb.x, xb.y, xb.z, xb.w};
      float wv[8];
      if (inter) {
#pragma unroll
        for (int jj = 0; jj < 8; jj++) {
          const float d = fmaf(-g, xs[jj], a);
          wv[jj] = __expf(-d * d);
          z += wv[jj];
        }
      } else {
#pragma unroll
        for (int jj = 0; jj < 8; jj++) {
          const float d = fmaf(-g, xs[jj], a);
          const float e = __expf(-d * d);
          wv[jj] = (k0 + jj < c) ? e : 0.f;
          z += wv[jj];
        }
      }
      PK8 ph, pl;
#pragma unroll
      for (int p2 = 0; p2 < 4; p2++) {
        const uint u0 = __float_as_uint(wv[2 * p2]);
        const uint u1 = __float_as_uint(wv[2 * p2 + 1]);
        const uint h0 = u0 & 0xffff0000u, h1 = u1 & 0xffff0000u;
        const float l0f = wv[2 * p2] - __uint_as_float(h0);
        const float l1f = wv[2 * p2 + 1] - __uint_as_float(h1);
        ph.i[p2] = (int)((h0 >> 16) | h1);
        pl.i[p2] = (int)((__float_as_uint(l0f) >> 16) | (__float_as_uint(l1f) & 0xffff0000u));
      }
      const bf16x8 ahi = ph.s, alo = pl.s;
      const int goff = (ch * 8 + kk * 4) * 16;  // l-group offset (ushorts)
#pragma unroll
      for (int hh = 0; hh < 2; hh++) {
#pragma unroll
        for (int ct = 0; ct < 2; ct++) {
          const ushort_t* p = Vq[hh * 2 + ct] + goff;
          const bf16x8 bh = *(const bf16x8*)p;
          const bf16x8 bl = *(const bf16x8*)(p + 8);
          acc[hh * 2 + ct] =
              __builtin_amdgcn_mfma_f32_16x16x32_bf16(ahi, bh, acc[hh * 2 + ct], 0, 0, 0);
          acc[hh * 2 + ct] =
              __builtin_amdgcn_mfma_f32_16x16x32_bf16(ahi, bl, acc[hh * 2 + ct], 0, 0, 0);
          acc[hh * 2 + ct] =
              __builtin_amdgcn_mfma_f32_16x16x32_bf16(alo, bh, acc[hh * 2 + ct], 0, 0, 0);
        }
      }
    }
  }

  // z: reduce q-replicas (each octet covered disjoint l)
  z += __shfl_xor(z, 16, 64);
  z += __shfl_xor(z, 32, 64);

  // D layout per acc[hh*2+ct]: col = hh*32 + ct*16 + m16, row = q*4 + rr
#pragma unroll
  for (int rr = 0; rr < 4; rr++) {
    const int row = q * 4 + rr;
    const float zr = __shfl(z, row, 64);
    const int cr = __shfl(c, row, 64);
    const float inv = 1.0f / (zr + (float)(L - cr));
#pragma unroll
    for (int hh = 0; hh < 2; hh++) {
#pragma unroll
      for (int ct = 0; ct < 2; ct++) {
        out[(size_t)(tbase + row) * 64 + hh * 32 + ct * 16 + m16] =
            acc[hh * 2 + ct][rr] * inv;
      }
    }
  }
}

}  // namespace

extern "C" void kernel_launch(void* const* d_in, const int* in_sizes, int n_in,
                              void* d_out, int out_size, void* d_ws, size_t ws_size,
                              hipStream_t stream) {
  const float* ref_data = (const float*)d_in[0];
  const float* ref_t = (const float*)d_in[1];
  const float* m1_data = (const float*)d_in[2];
  const float* m1_t = (const float*)d_in[3];
  const float* m2_data = (const float*)d_in[4];
  const float* m2_t = (const float*)d_in[5];
  const float* m3_data = (const float*)d_in[6];
  const float* m3_t = (const float*)d_in[7];
  const float* Wq = (const float*)d_in[8];
  const float* Wk1 = (const float*)d_in[9];
  const float* bk1 = (const float*)d_in[10];
  const float* Wv1 = (const float*)d_in[11];
  const float* bv1 = (const float*)d_in[12];
  const float* lt1 = (const float*)d_in[13];
  const float* Wk2 = (const float*)d_in[14];
  const float* bk2 = (const float*)d_in[15];
  const float* Wv2 = (const float*)d_in[16];
  const float* bv2 = (const float*)d_in[17];
  const float* lt2 = (const float*)d_in[18];
  const float* Wk3 = (const float*)d_in[19];
  const float* bk3 = (const float*)d_in[20];
  const float* Wv3 = (const float*)d_in[21];
  const float* bv3 = (const float*)d_in[22];
  const float* lt3 = (const float*)d_in[23];

  float* ws = (float*)d_ws;
  ushort_t* VI = (ushort_t*)ws;                 // VI_SZ float slots
  float* Xw = ws + VI_SZ;                       // X_SZ
  float* Aq = Xw + X_SZ;                        // A_SZ
  float* Gq = Aq + A_SZ;                        // A_SZ
  int* Cq = (int*)(Gq + A_SZ);                  // A_SZ

  mm_prep<<<dim3(576), dim3(256), 0, stream>>>(
      ref_data, ref_t, m1_data, m1_t, m2_data, m2_t, m3_data, m3_t, Wq,
      Wk1, bk1, Wv1, bv1, lt1, Wk2, bk2, Wv2, bv2, lt2, Wk3, bk3, Wv3, bv3, lt3,
      Aq, Gq, Cq, VI, Xw);
  mm_attn_main<<<dim3(12 * 64), dim3(128), 0, stream>>>(
      VI, Xw, Aq, Gq, Cq, (float*)d_out);
}

// Round 4
// 148.444 us; speedup vs baseline: 1.4137x; 1.4137x over previous
//
#include <hip/hip_runtime.h>

namespace {

typedef unsigned int uint;
typedef unsigned short ushort_t;
typedef __attribute__((ext_vector_type(8))) short bf16x8;
typedef __attribute__((ext_vector_type(4))) float f32x4;

constexpr int N = 4, T = 2048, L = 2048;
constexpr int DQIN = 32, DQK = 64;

// workspace layout (float-sized slots); ~6.5 MB
constexpr int VI_SZ = 3 * N * 64 * L;  // ushort pairs [dim row][8l-group][hi8|lo8], as float slots
constexpr int X_SZ = 3 * N * L;
constexpr int A_SZ = 3 * N * T;

union PK8 { int i[4]; bf16x8 s; };

// =================== fused prep kernel ===================
// [0,96): Q->a,g (one thread per (m,n,t)); [96,192): binary searches;
// [192,1728): V transform, 4 rows/thread (was 16) -> 4x the waves; the
// 512-serial-broadcast-load chain per thread was latency-bound at 1.5
// waves/SIMD.
__global__ __launch_bounds__(256) void mm_prep(
    const float* __restrict__ ref_data, const float* __restrict__ ref_t,
    const float* __restrict__ d1, const float* __restrict__ t1,
    const float* __restrict__ d2, const float* __restrict__ t2,
    const float* __restrict__ d3, const float* __restrict__ t3,
    const float* __restrict__ Wq,
    const float* __restrict__ Wk1, const float* __restrict__ bk1,
    const float* __restrict__ Wv1, const float* __restrict__ bv1, const float* __restrict__ lt1,
    const float* __restrict__ Wk2, const float* __restrict__ bk2,
    const float* __restrict__ Wv2, const float* __restrict__ bv2, const float* __restrict__ lt2,
    const float* __restrict__ Wk3, const float* __restrict__ bk3,
    const float* __restrict__ Wv3, const float* __restrict__ bv3, const float* __restrict__ lt3,
    float* __restrict__ Aq, float* __restrict__ Gq, int* __restrict__ Cq,
    ushort_t* __restrict__ VI, float* __restrict__ X) {
  const int b = blockIdx.x;
  const int tid = threadIdx.x;

  if (b < 96) {
    // ---- Q path, one thread per (m, n*T+t); block-uniform modality m = b/32 ----
    const int m = b >> 5;
    const int idx = (b & 31) * 256 + tid;  // n*T + t
    __shared__ float sWq[DQIN * DQK];
    __shared__ float sWk[DQK];
    __shared__ float sbk[DQK];
    const float* Wk = (m == 0) ? Wk1 : (m == 1 ? Wk2 : Wk3);
    const float* bk = (m == 0) ? bk1 : (m == 1 ? bk2 : bk3);
    const float* lt = (m == 0) ? lt1 : (m == 1 ? lt2 : lt3);
    for (int i = tid; i < DQIN * DQK; i += 256) sWq[i] = Wq[i];
    if (tid < DQK) { sWk[tid] = Wk[tid]; sbk[tid] = bk[tid]; }
    __syncthreads();
    float x[DQIN];
    const float* rp = ref_data + idx * DQIN;
#pragma unroll
    for (int i = 0; i < DQIN; i++) x[i] = rp[i];
    float qr[DQK];
#pragma unroll
    for (int j = 0; j < DQK; j += 4) {
      float4 acc4 = make_float4(0.f, 0.f, 0.f, 0.f);
#pragma unroll
      for (int i = 0; i < DQIN; i++) {
        const float4 w = *(const float4*)&sWq[i * DQK + j];
        acc4.x = fmaf(x[i], w.x, acc4.x);
        acc4.y = fmaf(x[i], w.y, acc4.y);
        acc4.z = fmaf(x[i], w.z, acc4.z);
        acc4.w = fmaf(x[i], w.w, acc4.w);
      }
      qr[j] = acc4.x; qr[j + 1] = acc4.y; qr[j + 2] = acc4.z; qr[j + 3] = acc4.w;
    }
    const float rs = __expf(-0.5f * lt[0]);
    float g = 0.f, h = 0.f;
#pragma unroll
    for (int j = 1; j < DQK; j++) {
      g = fmaf(qr[j], sWk[j - 1], g);
      h = fmaf(qr[j], sbk[j - 1], h);
    }
    g += sWk[DQK - 1];
    h += sbk[DQK - 1];
    Aq[m * (N * T) + idx] = (qr[0] - h) * rs;
    Gq[m * (N * T) + idx] = g * rs;
  } else if (b < 192) {
    const int sidx = (b - 96) * 256 + tid;
    const int m = sidx >> 13;
    const int nt = sidx & 8191;
    const int n = nt >> 11;
    const float rt = ref_t[nt];
    const float* tml = ((m == 0) ? t1 : (m == 1 ? t2 : t3)) + n * L;
    int lo = 0, hi = L;
    while (lo < hi) {
      const int mid = (lo + hi) >> 1;
      if (tml[mid] <= rt) lo = mid + 1; else hi = mid;
    }
    Cq[m * 8192 + nt] = lo;
  } else {
    const int vb = b - 192;           // 0..1535
    const int mn = vb >> 7;           // m*N+n
    const int m = mn >> 2, n = mn & 3;
    const int lseg = (vb & 127) * 16;
    const float* dm = (m == 0) ? d1 : (m == 1 ? d2 : d3);
    const float* Wv = (m == 0) ? Wv1 : (m == 1 ? Wv2 : Wv3);
    const float* bv = (m == 0) ? bv1 : (m == 1 ? bv2 : bv3);
    const int cdim = tid & 63;
    const int qq = tid >> 6;          // 0..3
    const int l0 = lseg + qq * 4;     // 4 rows per thread

    float Wc[32];
#pragma unroll
    for (int i = 0; i < 32; i++) Wc[i] = Wv[i * 64 + cdim];
    const float bvc = bv[cdim];

    uint hi16[4], lo16[4];
#pragma unroll
    for (int k = 0; k < 4; k++) {
      const float* dp = dm + (size_t)(n * L + l0 + k) * 34;
      float acc = bvc;
#pragma unroll
      for (int i = 0; i < 32; i++) acc = fmaf(dp[i], Wc[i], acc);
      uint u = __float_as_uint(acc);
      uint h = (u + 0x7fffu + ((u >> 16) & 1u)) & 0xffff0000u;
      float res = acc - __uint_as_float(h);
      uint ul = __float_as_uint(res);
      uint hl = (ul + 0x7fffu + ((ul >> 16) & 1u)) >> 16;
      hi16[k] = h >> 16;
      lo16[k] = hl;
    }
    const int pkh0 = (int)(hi16[0] | (hi16[1] << 16));
    const int pkh1 = (int)(hi16[2] | (hi16[3] << 16));
    const int pkl0 = (int)(lo16[0] | (lo16[1] << 16));
    const int pkl1 = (int)(lo16[2] | (lo16[3] << 16));
    // VI row layout per 8l-group: [hi8 (16 ushorts? no: 8)][lo8]; 4 rows =
    // half a group at halfsel = (l0>>2)&1.
    ushort_t* dst = VI + (size_t)(mn * 64 + cdim) * (2 * L) +
                    (l0 >> 3) * 16 + ((l0 >> 2) & 1) * 4;
    *(int2*)dst = make_int2(pkh0, pkh1);
    *(int2*)(dst + 8) = make_int2(pkl0, pkl1);

    if (tid < 16) {
      const int l = lseg + tid;
      X[mn * L + l] = dm[(size_t)(n * L + l) * 34 + 33];
    }
  }
}

// =================== main attention kernel ===================
// block = 2 waves, ONE rowgroup (16 t-rows) x full 64 dims; grid 12*128=1536
// (heavy-first -> 4 blocks/CU resident + 512-block LPT refill queue, the r0
// structure that balanced the makespan). The two waves split each 64-l
// chunk's l-range 32/32 (wave w takes k-tile [w*32, w*32+32)), so the exp+
// pack VALU work is computed exactly once grid-wide (the r1 fold kept) while
// the grid stays at 1536 (r1/r2 halved it to 768 -> 3/CU, no queue ->
// occupancy collapsed to 8.5% and latency was exposed). Partial accumulators
// and z combined across the wave pair via a 4KB LDS exchange at the end;
// each wave writes 32 of the 64 output dims. Staging: 2x16KB ring (full
// 64-dim slab per 64-l chunk), counted vmcnt(8), 2 barriers/chunk; sx 8KB
// -> LDS 40KB.
__device__ inline void stage_chunk(ushort_t* dstbuf, const ushort_t* VIb, int ch,
                                   int w, int lane) {
#pragma unroll
  for (int i = 0; i < 8; i++) {
    const int n = (w * 8 + i) * 64 + lane;   // lds 16B-unit index 0..1023
    const int d = n >> 4;                    // dim row 0..63
    const int s = n & 15;                    // swizzled unit slot
    const int u = (s - d) & 15;              // original unit within row-chunk
    const ushort_t* src = VIb + (size_t)d * 4096 + ch * 128 + u * 8;
    __builtin_amdgcn_global_load_lds(
        (const __attribute__((address_space(1))) void*)src,
        (__attribute__((address_space(3))) void*)(dstbuf + n * 8),
        16, 0, 0);
  }
}

__global__ __launch_bounds__(128, 2) void mm_attn_main(
    const ushort_t* __restrict__ VI, const float* __restrict__ X,
    const float* __restrict__ Aq, const float* __restrict__ Gq, const int* __restrict__ Cq,
    float* __restrict__ out) {
  __shared__ ushort_t sbuf[2][8192];  // 2 x 16KB chunk slabs (64 dims x 64 l)
  __shared__ float sx[2048];          // full X row for this mn (8KB) -> 40KB

  const int b = blockIdx.x;
  const int mn = b % 12;
  const int rg = 127 - (b / 12);  // heavy rowgroups (large c) first

  const int tid = threadIdx.x;
  const int lane = tid & 63;
  const int w = tid >> 6;              // wave 0/1: l-half of each chunk
  const int q = lane >> 4;
  const int m16 = lane & 15;

  const int tbase = mn * T + rg * 16;

  const int c = Cq[tbase + m16];
  const int cmax = __shfl(c, 15, 64);  // c monotone in t
  const int cmin = __shfl(c, 0, 64);
  const int nch = (cmax + 63) >> 6;    // block-uniform chunk count

  const float a = Aq[tbase + m16];
  const float g = Gq[tbase + m16];

  f32x4 acc[4];  // [hh*2+ct]: cols hh*32 + ct*16 + m16 (partial over this wave's l)
#pragma unroll
  for (int i = 0; i < 4; i++) acc[i] = (f32x4){0.f, 0.f, 0.f, 0.f};
  float z = 0.f;

  const ushort_t* VIb = VI + (size_t)(mn * 64) * 4096;
  const float* xg = X + mn * L;

  // hoisted swizzled B-fragment offsets (ushorts): dim row d, unit u stored
  // at d*16 + ((u+d)&15); this wave reads groups g2 = w*4+q (hi/lo parts).
  int oh[2][2], ol[2][2];
#pragma unroll
  for (int hh = 0; hh < 2; hh++) {
#pragma unroll
    for (int ct = 0; ct < 2; ct++) {
      const int d = hh * 32 + ct * 16 + m16;
      const int u0 = (w * 4 + q) * 2;
      oh[hh][ct] = d * 128 + (((u0 + 0) + d) & 15) * 8;
      ol[hh][ct] = d * 128 + (((u0 + 1) + d) & 15) * 8;
    }
  }

  // prologue: stage X (8KB) + chunk 0
#pragma unroll
  for (int i = 0; i < 4; i++) {
    const float* src = xg + (i * 128 + tid) * 4;
    __builtin_amdgcn_global_load_lds(
        (const __attribute__((address_space(1))) void*)src,
        (__attribute__((address_space(3))) void*)(sx + (i * 128 + tid) * 4),
        16, 0, 0);
  }
  if (nch > 0) stage_chunk(sbuf[0], VIb, 0, w, lane);

  for (int ch = 0; ch < nch; ch++) {
    if (ch + 1 < nch) {
      stage_chunk(sbuf[(ch + 1) & 1], VIb, ch + 1, w, lane);
      asm volatile("s_waitcnt vmcnt(8)" ::: "memory");  // this chunk done; next in flight
    } else {
      asm volatile("s_waitcnt vmcnt(0)" ::: "memory");
    }
    asm volatile("" ::: "memory");
    __builtin_amdgcn_s_barrier();  // both waves' halves staged
    asm volatile("" ::: "memory");

    const int kbase = (ch << 6) + w * 32;  // this wave's 32-l k-tile
    if (kbase < cmax) {
      const int k0 = kbase + q * 8;
      const float4 xa = *(const float4*)&sx[k0];
      const float4 xb = *(const float4*)&sx[k0 + 4];
      const float xs[8] = {xa.x, xa.y, xa.z, xa.w, xb.x, xb.y, xb.z, xb.w};
      float wv[8];
      if (kbase + 32 <= cmin) {  // all 16 rows fully active in this k-tile
#pragma unroll
        for (int jj = 0; jj < 8; jj++) {
          const float d = fmaf(-g, xs[jj], a);
          wv[jj] = __expf(-d * d);
          z += wv[jj];
        }
      } else {
#pragma unroll
        for (int jj = 0; jj < 8; jj++) {
          const float d = fmaf(-g, xs[jj], a);
          const float e = __expf(-d * d);
          wv[jj] = (k0 + jj < c) ? e : 0.f;
          z += wv[jj];
        }
      }
      PK8 ph, pl;
#pragma unroll
      for (int p2 = 0; p2 < 4; p2++) {
        const uint u0 = __float_as_uint(wv[2 * p2]);
        const uint u1 = __float_as_uint(wv[2 * p2 + 1]);
        const uint h0 = u0 & 0xffff0000u, h1 = u1 & 0xffff0000u;
        const float l0f = wv[2 * p2] - __uint_as_float(h0);
        const float l1f = wv[2 * p2 + 1] - __uint_as_float(h1);
        ph.i[p2] = (int)((h0 >> 16) | h1);
        pl.i[p2] = (int)((__float_as_uint(l0f) >> 16) | (__float_as_uint(l1f) & 0xffff0000u));
      }
      const bf16x8 ahi = ph.s, alo = pl.s;
      const ushort_t* buf = sbuf[ch & 1];
#pragma unroll
      for (int hh = 0; hh < 2; hh++) {
#pragma unroll
        for (int ct = 0; ct < 2; ct++) {
          const bf16x8 bh = *(const bf16x8*)(buf + oh[hh][ct]);
          const bf16x8 bl = *(const bf16x8*)(buf + ol[hh][ct]);
          acc[hh * 2 + ct] =
              __builtin_amdgcn_mfma_f32_16x16x32_bf16(ahi, bh, acc[hh * 2 + ct], 0, 0, 0);
          acc[hh * 2 + ct] =
              __builtin_amdgcn_mfma_f32_16x16x32_bf16(ahi, bl, acc[hh * 2 + ct], 0, 0, 0);
          acc[hh * 2 + ct] =
              __builtin_amdgcn_mfma_f32_16x16x32_bf16(alo, bh, acc[hh * 2 + ct], 0, 0, 0);
        }
      }
    }

    asm volatile("" ::: "memory");
    __builtin_amdgcn_s_barrier();  // reads done before next stage overwrites
    asm volatile("" ::: "memory");
  }

  // z: reduce q-replicas (each octet covered disjoint l within this wave)
  z += __shfl_xor(z, 16, 64);
  z += __shfl_xor(z, 32, 64);

  // cross-wave combine via LDS: wave w outputs dims [w*32, w*32+32) and
  // hands its partial of the OTHER half (quadrants hh = w^1) across.
  float* sc = (float*)sbuf;
  const int ow = w ^ 1;
#pragma unroll
  for (int p = 0; p < 2; p++)
    *(f32x4*)&sc[((w * 2 + p) * 64 + lane) * 4] = acc[ow * 2 + p];
  sc[1024 + w * 64 + lane] = z;
  __syncthreads();
  const float zt = z + sc[1024 + ow * 64 + lane];
  f32x4 r[2];
#pragma unroll
  for (int p = 0; p < 2; p++)
    r[p] = acc[w * 2 + p] + *(const f32x4*)&sc[((ow * 2 + p) * 64 + lane) * 4];

#pragma unroll
  for (int rr = 0; rr < 4; rr++) {
    const int row = q * 4 + rr;
    const float zr = __shfl(zt, row, 64);
    const int cr = __shfl(c, row, 64);
    const float inv = 1.0f / (zr + (float)(L - cr));
#pragma unroll
    for (int p = 0; p < 2; p++) {
      out[(size_t)(tbase + row) * 64 + w * 32 + p * 16 + m16] = r[p][rr] * inv;
    }
  }
}

}  // namespace

extern "C" void kernel_launch(void* const* d_in, const int* in_sizes, int n_in,
                              void* d_out, int out_size, void* d_ws, size_t ws_size,
                              hipStream_t stream) {
  const float* ref_data = (const float*)d_in[0];
  const float* ref_t = (const float*)d_in[1];
  const float* m1_data = (const float*)d_in[2];
  const float* m1_t = (const float*)d_in[3];
  const float* m2_data = (const float*)d_in[4];
  const float* m2_t = (const float*)d_in[5];
  const float* m3_data = (const float*)d_in[6];
  const float* m3_t = (const float*)d_in[7];
  const float* Wq = (const float*)d_in[8];
  const float* Wk1 = (const float*)d_in[9];
  const float* bk1 = (const float*)d_in[10];
  const float* Wv1 = (const float*)d_in[11];
  const float* bv1 = (const float*)d_in[12];
  const float* lt1 = (const float*)d_in[13];
  const float* Wk2 = (const float*)d_in[14];
  const float* bk2 = (const float*)d_in[15];
  const float* Wv2 = (const float*)d_in[16];
  const float* bv2 = (const float*)d_in[17];
  const float* lt2 = (const float*)d_in[18];
  const float* Wk3 = (const float*)d_in[19];
  const float* bk3 = (const float*)d_in[20];
  const float* Wv3 = (const float*)d_in[21];
  const float* bv3 = (const float*)d_in[22];
  const float* lt3 = (const float*)d_in[23];

  float* ws = (float*)d_ws;
  ushort_t* VI = (ushort_t*)ws;                 // VI_SZ float slots
  float* Xw = ws + VI_SZ;                       // X_SZ
  float* Aq = Xw + X_SZ;                        // A_SZ
  float* Gq = Aq + A_SZ;                        // A_SZ
  int* Cq = (int*)(Gq + A_SZ);                  // A_SZ

  mm_prep<<<dim3(1728), dim3(256), 0, stream>>>(
      ref_data, ref_t, m1_data, m1_t, m2_data, m2_t, m3_data, m3_t, Wq,
      Wk1, bk1, Wv1, bv1, lt1, Wk2, bk2, Wv2, bv2, lt2, Wk3, bk3, Wv3, bv3, lt3,
      Aq, Gq, Cq, VI, Xw);
  mm_attn_main<<<dim3(12 * 128), dim3(128), 0, stream>>>(
      VI, Xw, Aq, Gq, Cq, (float*)d_out);
}